// Round 17
// baseline (95.787 us; speedup 1.0000x reference)
//
#include <hip/hip_runtime.h>
#include <hip/hip_bf16.h>

#define S_LEN 2048
#define DH 64
#define QBLK 128
#define KVBLK 64
#define LDPK 72   // K rows: 144B (16B-aligned)
#define LDPV 68   // V^T rows: 136B (8B-aligned) — R10 layout, 0-conflict verified

typedef __attribute__((ext_vector_type(4)))  float f32x4;
typedef __attribute__((ext_vector_type(16))) float f32x16;
typedef __attribute__((ext_vector_type(8)))  short short8v;
typedef __attribute__((ext_vector_type(4)))  unsigned uint4v;
typedef __attribute__((ext_vector_type(2)))  unsigned uint2v;

__device__ __forceinline__ unsigned cvt_pk(float a, float b) {
    unsigned r;
    asm("v_cvt_pk_bf16_f32 %0, %1, %2" : "=v"(r) : "v"(a), "v"(b));
    return r;
}

__global__ __launch_bounds__(512) void fa_fwd_kernel(
    const float* __restrict__ Q, const float* __restrict__ K,
    const float* __restrict__ V, float* __restrict__ O)
{
    const int tid  = threadIdx.x;
    const int lane = tid & 63;
    const int w    = tid >> 6;           // 0..7
    const int bh   = blockIdx.x & 63;    // same-bh blocks 64 apart -> same XCD
    const int pp   = blockIdx.x >> 6;    // 0..15
    const int p    = pp & 7;             // pair index
    const int half = pp >> 3;            // q-row half of each tile

    // KV-parity split: units = {heavy-half rows, light-half rows} x {par 0,1}.
    // All waves stage R10's shared monotonic stream [0,(16-p)*128); wave with
    // parity par computes only intervals s%2==par. End: in-block merge.
    const int u    = w & 3;              // 0,1: heavy tile; 2,3: light tile
    const int par  = w >> 2;             // interval parity this wave computes
    const int qb   = (u < 2) ? (15 - p) : p;
    const int q0   = qb * QBLK + half * 64 + (u & 1) * 32;   // wave's 32 q-rows
    const int kv_end = (16 - p) * QBLK;
    const int T    = kv_end >> 6;        // always even

    const size_t base = (size_t)bh * S_LEN * DH;
    const float* Qg = Q + base;
    const float* Kg = K + base;
    const float* Vg = V + base;
    float*       Og = O + base;

    __shared__ __align__(16) char smem[35840];
    short (*K_lds)[KVBLK][LDPK] = (short(*)[KVBLK][LDPK])smem;            // [2][64][72]
    short (*V_lds)[DH][LDPV]    = (short(*)[DH][LDPV])(smem + 18432);     // [2][64][68]
    float (*Mbuf)[64][34]       = (float(*)[64][34])smem;                 // [4][64][34] overlay

    const int q  = lane & 31;            // lane's q-column within the wave tile
    const int hi = lane >> 5;            // 0/1: k-slot half
    // staging decomposition (512 threads cover the 64x64 tile once) — R10 verbatim
    const int kr = tid >> 3;             // K row 0..63
    const int dc = (tid & 7) * 8;        // K col 0,8,...,56
    const int vd = tid & 63;             // V col (d)
    const int vg = tid >> 6;             // V row-group 0..7

    unsigned kpfu[4], vpf[4];

    auto prefetch = [&](int kvb) {
        const float* kp = Kg + (size_t)(kvb + kr) * DH + dc;
        f32x4 a = *(const f32x4*)kp;
        f32x4 b = *(const f32x4*)(kp + 4);
        kpfu[0] = cvt_pk(a[0], a[1]); kpfu[1] = cvt_pk(a[2], a[3]);
        kpfu[2] = cvt_pk(b[0], b[1]); kpfu[3] = cvt_pk(b[2], b[3]);
        #pragma unroll
        for (int i = 0; i < 4; ++i) {
            int kv = vg * 8 + i * 2;
            float x = Vg[(size_t)(kvb + kv) * DH + vd];
            float y = Vg[(size_t)(kvb + kv + 1) * DH + vd];
            vpf[i] = cvt_pk(x, y);
        }
    };

    auto stage = [&](int b) {
        uint4v uu = {kpfu[0], kpfu[1], kpfu[2], kpfu[3]};
        *(uint4v*)&K_lds[b][kr][dc] = uu;   // ds_write_b128
        #pragma unroll
        for (int i = 0; i < 4; ++i) {
            int kv = vg * 8 + i * 2;
            *(unsigned*)((char*)&V_lds[b][0][0] + vd * (LDPV * 2) + kv * 2) = vpf[i];
        }
    };

    const float qscale = 0.125f * 1.44269504088896340736f;

    // ---- Q B-fragments: lane supplies Q[d = ds*16 + hi*8 + j][q0+q], scaled ----
    short8v qfrag[4];
    #pragma unroll
    for (int ds = 0; ds < 4; ++ds) {
        const float* qp = Qg + (size_t)(q0 + q) * DH + ds * 16 + hi * 8;
        f32x4 a = *(const f32x4*)qp;
        f32x4 b = *(const f32x4*)(qp + 4);
        uint4v uu;
        uu[0] = cvt_pk(a[0] * qscale, a[1] * qscale);
        uu[1] = cvt_pk(a[2] * qscale, a[3] * qscale);
        uu[2] = cvt_pk(b[0] * qscale, b[1] * qscale);
        uu[3] = cvt_pk(b[2] * qscale, b[3] * qscale);
        qfrag[ds] = __builtin_bit_cast(short8v, uu);
    }

    f32x16 o_acc[2];   // O^T[dt*32 + rowmap][q]
    o_acc[0] = (f32x16)(0.f);
    o_acc[1] = (f32x16)(0.f);
    float m_run = -1e30f, l_run = 0.f;

    // verified 32x32 in-lane-softmax compute body (R10 verbatim)
    auto computeTile = [&](int cur, int kvb) {
        const short (*Kc)[LDPK] = K_lds[cur];
        const char* Vc = (const char*)&V_lds[cur][0][0];

        f32x16 s_acc[2];
        s_acc[0] = (f32x16)(0.f);
        s_acc[1] = (f32x16)(0.f);

        __builtin_amdgcn_s_setprio(1);
        #pragma unroll
        for (int ds = 0; ds < 4; ++ds) {
            #pragma unroll
            for (int kt = 0; kt < 2; ++kt) {
                short8v kf = *(const short8v*)&Kc[kt * 32 + q][ds * 16 + hi * 8];
                s_acc[kt] = __builtin_amdgcn_mfma_f32_32x32x16_bf16(
                    kf, qfrag[ds], s_acc[kt], 0, 0, 0);
            }
        }
        __builtin_amdgcn_s_setprio(0);

        const int qrow = q0 + q;
        if (kvb + KVBLK - 1 > q0) {
            #pragma unroll
            for (int kt = 0; kt < 2; ++kt)
                #pragma unroll
                for (int r = 0; r < 16; ++r) {
                    int kv = kvb + kt * 32 + (r & 3) + 8 * (r >> 2) + 4 * hi;
                    if (kv > qrow) s_acc[kt][r] = -1e30f;
                }
        }

        float tl = -1e30f;
        #pragma unroll
        for (int kt = 0; kt < 2; ++kt)
            #pragma unroll
            for (int r = 0; r < 16; ++r)
                tl = fmaxf(tl, s_acc[kt][r]);
        float tmax = fmaxf(tl, __shfl_xor(tl, 32));

        if (!__all(tmax <= m_run + 8.0f)) {
            float mnew = fmaxf(m_run, tmax);
            float corr = __builtin_amdgcn_exp2f(m_run - mnew);
            m_run = mnew;
            l_run *= corr;
            #pragma unroll
            for (int dt = 0; dt < 2; ++dt)
                #pragma unroll
                for (int r = 0; r < 16; ++r)
                    o_acc[dt][r] *= corr;   // in-lane: o col == this lane's q
        }

        float rsum = 0.f;
        #pragma unroll
        for (int kt = 0; kt < 2; ++kt)
            #pragma unroll
            for (int r = 0; r < 16; ++r) {
                float pe = __builtin_amdgcn_exp2f(s_acc[kt][r] - m_run);
                s_acc[kt][r] = pe;
                rsum += pe;
            }
        rsum += __shfl_xor(rsum, 32);
        l_run += rsum;

        unsigned pk_[2][8];
        #pragma unroll
        for (int kt = 0; kt < 2; ++kt)
            #pragma unroll
            for (int m = 0; m < 8; ++m)
                pk_[kt][m] = cvt_pk(s_acc[kt][2 * m], s_acc[kt][2 * m + 1]);

        __builtin_amdgcn_s_setprio(1);
        #pragma unroll
        for (int ss = 0; ss < 4; ++ss) {
            const int kt = ss >> 1, bofs = 4 * (ss & 1);
            uint4v bu = {pk_[kt][bofs], pk_[kt][bofs + 1],
                         pk_[kt][bofs + 2], pk_[kt][bofs + 3]};
            short8v pb = __builtin_bit_cast(short8v, bu);
            #pragma unroll
            for (int dt = 0; dt < 2; ++dt) {
                const char* vrow = Vc + (size_t)(dt * 32 + q) * (LDPV * 2);
                uint2v lo = *(const uint2v*)(vrow + (16 * ss + 4 * hi) * 2);
                uint2v h2 = *(const uint2v*)(vrow + (16 * ss + 8 + 4 * hi) * 2);
                uint4v au = {lo[0], lo[1], h2[0], h2[1]};
                short8v va = __builtin_bit_cast(short8v, au);
                o_acc[dt] = __builtin_amdgcn_mfma_f32_32x32x16_bf16(
                    va, pb, o_acc[dt], 0, 0, 0);
            }
        }
        __builtin_amdgcn_s_setprio(0);
    };

    prefetch(0);
    stage(0);
    int cur = 0;
    __syncthreads();

    #pragma unroll 1
    for (int s = 0; s < T; ++s) {
        const bool have = (s + 1) < T;
        if (have) prefetch((s + 1) * 64);           // lands under compute

        if ((s & 1) == par && s * 64 <= q0)
            computeTile(cur, s * 64);

        if (have) {
            stage(cur ^ 1);
            __syncthreads();
        }
        cur ^= 1;
    }

    // ---- merge parity partials (R13-verified formula; LDS overlay on K/V) ----
    __syncthreads();                     // all K/V LDS reads complete
    if (par == 1) {
        float* mb = Mbuf[u][lane];
        mb[0] = m_run;
        mb[1] = l_run;
        #pragma unroll
        for (int dt = 0; dt < 2; ++dt)
            #pragma unroll
            for (int r = 0; r < 16; ++r)
                mb[2 + dt * 16 + r] = o_acc[dt][r];
    }
    __syncthreads();
    if (par == 0) {
        const float* mb = Mbuf[u][lane];
        float mB = mb[0], lB = mb[1];
        float mN = fmaxf(m_run, mB);
        float sA = __builtin_amdgcn_exp2f(m_run - mN);   // A (even, incl s=0): never empty
        float sB = __builtin_amdgcn_exp2f(mB - mN);      // 0 if B empty
        float inv = 1.0f / (l_run * sA + lB * sB);
        float* orow = Og + (size_t)(q0 + q) * DH;
        #pragma unroll
        for (int dt = 0; dt < 2; ++dt) {
            #pragma unroll
            for (int g = 0; g < 4; ++g) {
                f32x4 ov;
                #pragma unroll
                for (int i2 = 0; i2 < 4; ++i2)
                    ov[i2] = (o_acc[dt][4 * g + i2] * sA +
                              mb[2 + dt * 16 + 4 * g + i2] * sB) * inv;
                *(f32x4*)(orow + dt * 32 + 8 * g + 4 * hi) = ov;
            }
        }
    }
}

extern "C" void kernel_launch(void* const* d_in, const int* in_sizes, int n_in,
                              void* d_out, int out_size, void* d_ws, size_t ws_size,
                              hipStream_t stream) {
    const float* q = (const float*)d_in[0];
    const float* k = (const float*)d_in[1];
    const float* v = (const float*)d_in[2];
    float* out = (float*)d_out;
    // 1024 blocks x 512 threads: 64 (b,h) x 8 pairs {15-p,p} x 2 q-row halves;
    // KV-parity split inside each block -> up to 4 blocks/CU (32 waves/CU)
    fa_fwd_kernel<<<dim3(1024), dim3(512), 0, stream>>>(q, k, v, out);
}

// Round 18
// 75.266 us; speedup vs baseline: 1.2726x; 1.2726x over previous
//
#include <hip/hip_runtime.h>
#include <hip/hip_bf16.h>

#define S_LEN 2048
#define DH 64
#define QBLK 128
#define KVBLK 64
#define LDPK 72   // K rows: 144B (16B-aligned)
#define LDPV 68   // V^T rows: 136B (8B-aligned) — R10 0-conflict layout

typedef __attribute__((ext_vector_type(4)))  float f32x4;
typedef __attribute__((ext_vector_type(16))) float f32x16;
typedef __attribute__((ext_vector_type(8)))  short short8v;
typedef __attribute__((ext_vector_type(4)))  unsigned uint4v;
typedef __attribute__((ext_vector_type(2)))  unsigned uint2v;

__device__ __forceinline__ unsigned cvt_pk(float a, float b) {
    unsigned r;
    asm("v_cvt_pk_bf16_f32 %0, %1, %2" : "=v"(r) : "v"(a), "v"(b));
    return r;
}

__global__ __launch_bounds__(512) void fa_fwd_kernel(
    const float* __restrict__ Q, const float* __restrict__ K,
    const float* __restrict__ V, float* __restrict__ O)
{
    const int tid  = threadIdx.x;
    const int lane = tid & 63;
    const int w    = tid >> 6;          // 0..7 waves
    // CU-balance remap (ONLY change vs R10): under round-robin dispatch, bid and
    // bid+256 co-reside on one CU. Give them pair-indices p and 7-p -> per-CU
    // total = (32-2p)+(18+2p) = 50 intervals, uniform. Same-bh blocks stay 32*k
    // apart -> same XCD -> KV L2 sharing preserved.
    const int bid  = blockIdx.x;
    const int lo8  = (bid >> 5) & 7;
    const int p    = (bid < 256) ? lo8 : 7 - lo8;
    const int bh   = (bid & 31) | ((bid >> 8) << 5);

    // concurrent pair: waves 0-3 -> q-tile (15-p), waves 4-7 -> q-tile p;
    // one monotonic KV stream [0, (16-p)*128). Past-extent waves stay producers.
    const int qb = (w < 4) ? (15 - p) : p;
    const int q0 = qb * QBLK + (w & 3) * 32;      // wave's first q-row
    const int kv_end = (16 - p) * QBLK;           // stream extent (heavy tile's)

    const size_t base = (size_t)bh * S_LEN * DH;
    const float* Qg = Q + base;
    const float* Kg = K + base;
    const float* Vg = V + base;
    float*       Og = O + base;

    __shared__ __align__(16) short K_lds[2][KVBLK][LDPK];   // [buf][kv][d]
    __shared__ __align__(16) short V_lds[2][DH][LDPV];      // [buf][d][kv]

    const int q  = lane & 31;           // lane's q-column within the wave tile
    const int hi = lane >> 5;           // 0/1: k-slot half
    // staging decomposition (512 threads cover the 64x64 tile once)
    const int kr = tid >> 3;            // K row 0..63
    const int dc = (tid & 7) * 8;       // K col 0,8,...,56
    const int vd = tid & 63;            // V col (d)
    const int vg = tid >> 6;            // V row-group 0..7

    unsigned kpfu[4], vpf[4];

    auto prefetch = [&](int kvb) {
        const float* kp = Kg + (size_t)(kvb + kr) * DH + dc;
        f32x4 a = *(const f32x4*)kp;
        f32x4 b = *(const f32x4*)(kp + 4);
        kpfu[0] = cvt_pk(a[0], a[1]); kpfu[1] = cvt_pk(a[2], a[3]);
        kpfu[2] = cvt_pk(b[0], b[1]); kpfu[3] = cvt_pk(b[2], b[3]);
        #pragma unroll
        for (int i = 0; i < 4; ++i) {
            int kv = vg * 8 + i * 2;
            float x = Vg[(size_t)(kvb + kv) * DH + vd];
            float y = Vg[(size_t)(kvb + kv + 1) * DH + vd];
            vpf[i] = cvt_pk(x, y);
        }
    };

    auto stage = [&](int b) {
        uint4v u = {kpfu[0], kpfu[1], kpfu[2], kpfu[3]};
        *(uint4v*)&K_lds[b][kr][dc] = u;   // ds_write_b128
        #pragma unroll
        for (int i = 0; i < 4; ++i) {
            int kv = vg * 8 + i * 2;
            *(unsigned*)((char*)&V_lds[b][0][0] + vd * (LDPV * 2) + kv * 2) = vpf[i];
        }
    };

    const float qscale = 0.125f * 1.44269504088896340736f;

    // ---- Q B-fragments: lane supplies Q[d = ds*16 + hi*8 + j][q0+q], scaled ----
    short8v qfrag[4];
    #pragma unroll
    for (int ds = 0; ds < 4; ++ds) {
        const float* qp = Qg + (size_t)(q0 + q) * DH + ds * 16 + hi * 8;
        f32x4 a = *(const f32x4*)qp;
        f32x4 b = *(const f32x4*)(qp + 4);
        uint4v u;
        u[0] = cvt_pk(a[0] * qscale, a[1] * qscale);
        u[1] = cvt_pk(a[2] * qscale, a[3] * qscale);
        u[2] = cvt_pk(b[0] * qscale, b[1] * qscale);
        u[3] = cvt_pk(b[2] * qscale, b[3] * qscale);
        qfrag[ds] = __builtin_bit_cast(short8v, u);
    }

    f32x16 o_acc[2];   // O^T[dt*32 + rowmap][q]
    o_acc[0] = (f32x16)(0.f);
    o_acc[1] = (f32x16)(0.f);
    float m_run = -1e30f, l_run = 0.f;

    prefetch(0);
    stage(0);
    int cur = 0;
    __syncthreads();

    #pragma unroll 1
    for (int kvb = 0; kvb < kv_end; kvb += KVBLK) {
        int nkv = kvb + KVBLK;
        const bool have = nkv < kv_end;
        if (have) prefetch(nkv);   // global->reg, lands under compute

        if (kvb <= q0) {           // this wave still inside its causal extent
            const short (*Kc)[LDPK] = K_lds[cur];
            const char* Vc = (const char*)&V_lds[cur][0][0];

            // ---- swapped QK^T: S^T[kv][q] = K·Q^T, two 32-kv tiles ----
            f32x16 s_acc[2];
            s_acc[0] = (f32x16)(0.f);
            s_acc[1] = (f32x16)(0.f);

            __builtin_amdgcn_s_setprio(1);
            #pragma unroll
            for (int ds = 0; ds < 4; ++ds) {
                #pragma unroll
                for (int kt = 0; kt < 2; ++kt) {
                    short8v kf = *(const short8v*)&Kc[kt * 32 + q][ds * 16 + hi * 8];
                    s_acc[kt] = __builtin_amdgcn_mfma_f32_32x32x16_bf16(
                        kf, qfrag[ds], s_acc[kt], 0, 0, 0);
                }
            }
            __builtin_amdgcn_s_setprio(0);

            // ---- mask (diagonal tiles only): kv = kvb+32kt+(r&3)+8(r>>2)+4hi ----
            const int qrow = q0 + q;
            if (kvb + KVBLK - 1 > q0) {
                #pragma unroll
                for (int kt = 0; kt < 2; ++kt)
                    #pragma unroll
                    for (int r = 0; r < 16; ++r) {
                        int kv = kvb + kt * 32 + (r & 3) + 8 * (r >> 2) + 4 * hi;
                        if (kv > qrow) s_acc[kt][r] = -1e30f;
                    }
            }

            // ---- softmax: fully in-lane except ONE shfl_xor(32) each ----
            float tl = -1e30f;
            #pragma unroll
            for (int kt = 0; kt < 2; ++kt)
                #pragma unroll
                for (int r = 0; r < 16; ++r)
                    tl = fmaxf(tl, s_acc[kt][r]);
            float tmax = fmaxf(tl, __shfl_xor(tl, 32));

            if (!__all(tmax <= m_run + 8.0f)) {
                float mnew = fmaxf(m_run, tmax);
                float corr = __builtin_amdgcn_exp2f(m_run - mnew);
                m_run = mnew;
                l_run *= corr;
                #pragma unroll
                for (int dt = 0; dt < 2; ++dt)
                    #pragma unroll
                    for (int r = 0; r < 16; ++r)
                        o_acc[dt][r] *= corr;   // in-lane: o col == this lane's q
            }

            float rsum = 0.f;
            #pragma unroll
            for (int kt = 0; kt < 2; ++kt)
                #pragma unroll
                for (int r = 0; r < 16; ++r) {
                    float pe = __builtin_amdgcn_exp2f(s_acc[kt][r] - m_run);
                    s_acc[kt][r] = pe;
                    rsum += pe;
                }
            rsum += __shfl_xor(rsum, 32);
            l_run += rsum;

            // ---- pack P to bf16; registers land directly in B-frag k-slot order ----
            unsigned pk_[2][8];
            #pragma unroll
            for (int kt = 0; kt < 2; ++kt)
                #pragma unroll
                for (int m = 0; m < 8; ++m)
                    pk_[kt][m] = cvt_pk(s_acc[kt][2 * m], s_acc[kt][2 * m + 1]);

            // ---- PV: O^T += V^T · P ; A-frag k-order kv = 16s + (j&3)+8(j>>2)+4hi ----
            __builtin_amdgcn_s_setprio(1);
            #pragma unroll
            for (int s = 0; s < 4; ++s) {
                const int kt = s >> 1, bofs = 4 * (s & 1);
                uint4v bu = {pk_[kt][bofs], pk_[kt][bofs + 1],
                             pk_[kt][bofs + 2], pk_[kt][bofs + 3]};
                short8v pb = __builtin_bit_cast(short8v, bu);
                #pragma unroll
                for (int dt = 0; dt < 2; ++dt) {
                    const char* vrow = Vc + (size_t)(dt * 32 + q) * (LDPV * 2);
                    uint2v lo = *(const uint2v*)(vrow + (16 * s + 4 * hi) * 2);
                    uint2v h2 = *(const uint2v*)(vrow + (16 * s + 8 + 4 * hi) * 2);
                    uint4v au = {lo[0], lo[1], h2[0], h2[1]};
                    short8v va = __builtin_bit_cast(short8v, au);
                    o_acc[dt] = __builtin_amdgcn_mfma_f32_32x32x16_bf16(
                        va, pb, o_acc[dt], 0, 0, 0);
                }
            }
            __builtin_amdgcn_s_setprio(0);
        }

        if (have) {
            stage(cur ^ 1);
            __syncthreads();
        }
        cur ^= 1;
    }

    // ---- epilogue: all in-lane; O[q][d], d = dt*32 + 8g + 4hi + i ----
    float inv = 1.0f / l_run;
    float* orow = Og + (size_t)(q0 + q) * DH;
    #pragma unroll
    for (int dt = 0; dt < 2; ++dt) {
        #pragma unroll
        for (int g = 0; g < 4; ++g) {
            f32x4 ov = {o_acc[dt][4 * g] * inv,     o_acc[dt][4 * g + 1] * inv,
                        o_acc[dt][4 * g + 2] * inv, o_acc[dt][4 * g + 3] * inv};
            *(f32x4*)(orow + dt * 32 + 8 * g + 4 * hi) = ov;
        }
    }
}

extern "C" void kernel_launch(void* const* d_in, const int* in_sizes, int n_in,
                              void* d_out, int out_size, void* d_ws, size_t ws_size,
                              hipStream_t stream) {
    const float* q = (const float*)d_in[0];
    const float* k = (const float*)d_in[1];
    const float* v = (const float*)d_in[2];
    float* out = (float*)d_out;
    // 512 blocks x 512 threads: R10 structure + CU-balanced pair remap (p, 7-p)
    fa_fwd_kernel<<<dim3(512), dim3(512), 0, stream>>>(q, k, v, out);
}